// Round 4
// baseline (1354.715 us; speedup 1.0000x reference)
//
#include <hip/hip_runtime.h>
#include <hip/hip_bf16.h>

typedef __bf16 bf16x8 __attribute__((ext_vector_type(8)));
typedef float f32x4 __attribute__((ext_vector_type(4)));

__device__ __forceinline__ void gload16(const void* g, void* l) {
  __builtin_amdgcn_global_load_lds(
      (const __attribute__((address_space(1))) void*)g,
      (__attribute__((address_space(3))) void*)l, 16, 0, 0);
}

__device__ __forceinline__ unsigned short f2bf(float f) {
  __hip_bfloat16 h = __float2bfloat16(f);
  union { __hip_bfloat16 h; unsigned short u; } c;
  c.h = h;
  return c.u;
}

__device__ __forceinline__ void fwht16(float v[16]) {
#pragma unroll
  for (int s = 1; s < 16; s <<= 1) {
#pragma unroll
    for (int i = 0; i < 16; i++) {
      if ((i & s) == 0) {
        float a = v[i], b = v[i | s];
        v[i] = a + b;
        v[i | s] = a - b;
      }
    }
  }
}

// ---------------- FWHT #1: h1 = bf16( fwht(x*SU) / 2048 ) ----------------
__global__ __launch_bounds__(256) void fwht1_kernel(
    const float* __restrict__ x, const float* __restrict__ SU,
    unsigned short* __restrict__ H1) {
  __shared__ float lds[256 * 17];
  const int t = threadIdx.x;
  const size_t row = blockIdx.x;
  const float* xr = x + row * 4096;
  float v[16];
#pragma unroll
  for (int n2 = 0; n2 < 16; n2++) {
    int n = n2 * 256 + t;
    v[n2] = xr[n] * SU[n];
  }
  fwht16(v);
  const int n1 = t >> 4, n0 = t & 15;
#pragma unroll
  for (int j2 = 0; j2 < 16; j2++) lds[(j2 * 16 + n1) * 17 + n0] = v[j2];
  __syncthreads();
#pragma unroll
  for (int k = 0; k < 16; k++) v[k] = lds[((t >> 4) * 16 + k) * 17 + (t & 15)];
  fwht16(v);
#pragma unroll
  for (int k = 0; k < 16; k++) lds[((t >> 4) * 16 + k) * 17 + (t & 15)] = v[k];
  __syncthreads();
#pragma unroll
  for (int k = 0; k < 16; k++) v[k] = lds[t * 17 + k];
  fwht16(v);
  const float cst = 1.0f / 2048.0f;
  union { unsigned short u[16]; uint4 q[2]; } o;
#pragma unroll
  for (int k = 0; k < 16; k++) o.u[k] = f2bf(v[k] * cst);
  uint4* dst = (uint4*)(H1 + row * 4096 + (size_t)t * 16);
  dst[0] = o.q[0];
  dst[1] = o.q[1];
}

// ---------------- W conversion: Wb[m][n] = bf16(W[m][n] * Wscale[m]) -------
__global__ __launch_bounds__(256) void convw_kernel(
    const float4* __restrict__ W4, const float* __restrict__ Wscale,
    uint2* __restrict__ Wb4, int total4, int Nq) {
  int i = blockIdx.x * 256 + threadIdx.x;
  if (i >= total4) return;
  float4 w = W4[i];
  float s = Wscale[i / Nq];
  unsigned int lo = (unsigned)f2bf(w.x * s) | ((unsigned)f2bf(w.y * s) << 16);
  unsigned int hi = (unsigned)f2bf(w.z * s) | ((unsigned)f2bf(w.w * s) << 16);
  Wb4[i] = make_uint2(lo, hi);
}

// ---------------- GEMM: 256x256, BK=64, 8 waves, 8-phase PIPELINED ---------
// Register subtiles loaded ONE PHASE AHEAD (double-buffered frag sets), so
// LDS drain hides under the previous MFMA cluster. LDS row layouts permuted
// so each staged 128-row region is read by exactly one LOAD_A/LOAD_B:
//   A region h: lds_row = wm*64 + r64   (global row = wm*128 + h*64 + r64)
//   B region v: lds_row = wn*32 + c32   (global col = wn*64 + v*32 + c32)
// Gates: vmcnt(8) at end of the phase BEFORE the reads (barrier separates
// every wave's gate from any ds_read -> cross-wave safe). Tail: 4/2/0.

#define BARRIER()                          \
  do {                                     \
    asm volatile("" ::: "memory");         \
    __builtin_amdgcn_s_barrier();          \
    asm volatile("" ::: "memory");         \
  } while (0)
#define GATE10() asm volatile("s_waitcnt vmcnt(10)" ::: "memory")
#define GATE8() asm volatile("s_waitcnt vmcnt(8)" ::: "memory")
#define GATE4() asm volatile("s_waitcnt vmcnt(4)" ::: "memory")
#define GATE2() asm volatile("s_waitcnt vmcnt(2)" ::: "memory")
#define GATE0() asm volatile("s_waitcnt vmcnt(0)" ::: "memory")

// Stage A region h of buf d <- K-tile kt. 1024 chunks of 16B; 2 gloads/thread.
__device__ __forceinline__ void stage_A(const unsigned short* __restrict__ Ab,
                                        unsigned short* lr, int h, int kt,
                                        int tid, int K) {
#pragma unroll
  for (int i = 0; i < 2; i++) {
    int idx = i * 512 + tid;
    int rl = idx >> 3;                  // lds row in region (0..127)
    int c = (idx & 7) ^ (rl & 7);       // pre-swizzled source chunk
    int grow = (rl >> 6) * 128 + h * 64 + (rl & 63);
    gload16(Ab + (size_t)grow * K + (size_t)kt * 64 + c * 8, lr + idx * 8);
  }
}
// Stage B region v of buf d <- K-tile kt.
__device__ __forceinline__ void stage_B(const unsigned short* __restrict__ Bb,
                                        unsigned short* lr, int v, int kt,
                                        int tid, int K) {
#pragma unroll
  for (int i = 0; i < 2; i++) {
    int idx = i * 512 + tid;
    int rl = idx >> 3;
    int c = (idx & 7) ^ (rl & 7);
    int gcol = (rl >> 5) * 64 + v * 32 + (rl & 31);
    gload16(Bb + (size_t)gcol * K + (size_t)kt * 64 + c * 8, lr + idx * 8);
  }
}

#define STAGE_A(d, h, kt) stage_A(Abase, &As[d][(h)*8192], (h), (kt), tid, K)
#define STAGE_B(d, v, kt) stage_B(Bbase, &Bs[d][(v)*8192], (v), (kt), tid, K)

// Read A-half h of buf d into frag set dst[4][2] (region-local rows).
#define LOAD_A(d, h, dst)                                                     \
  {                                                                           \
    _Pragma("unroll") for (int i = 0; i < 4; i++) {                           \
      _Pragma("unroll") for (int ks = 0; ks < 2; ks++) {                      \
        int rl = wm * 64 + i * 16 + fr;                                       \
        int kc = ks * 4 + lhi;                                                \
        dst[i][ks] =                                                          \
            *(const bf16x8*)&As[d][(h)*8192 + rl * 64 + ((kc ^ (rl & 7)) << 3)]; \
      }                                                                       \
    }                                                                         \
  }

// Read B-slice v of buf d into frag set dst[2][2].
#define LOAD_B(d, v, dst)                                                     \
  {                                                                           \
    _Pragma("unroll") for (int j = 0; j < 2; j++) {                           \
      _Pragma("unroll") for (int ks = 0; ks < 2; ks++) {                      \
        int rl = wn * 32 + j * 16 + fr;                                       \
        int kc = ks * 4 + lhi;                                                \
        dst[j][ks] =                                                          \
            *(const bf16x8*)&Bs[d][(v)*8192 + rl * 64 + ((kc ^ (rl & 7)) << 3)]; \
      }                                                                       \
    }                                                                         \
  }

#define MFMA_PH(ho, vo, aset, bset)                                           \
  {                                                                           \
    __builtin_amdgcn_s_setprio(1);                                            \
    _Pragma("unroll") for (int i = 0; i < 4; i++)                             \
      _Pragma("unroll") for (int j = 0; j < 2; j++)                           \
        _Pragma("unroll") for (int ks = 0; ks < 2; ks++)                      \
          acc[(ho)*4 + i][(vo)*2 + j] =                                       \
              __builtin_amdgcn_mfma_f32_16x16x32_bf16(                        \
                  aset[i][ks], bset[j][ks], acc[(ho)*4 + i][(vo)*2 + j], 0,   \
                  0, 0);                                                      \
    __builtin_amdgcn_s_setprio(0);                                            \
  }

__global__ __launch_bounds__(512, 2) void gemm8_kernel(
    const unsigned short* __restrict__ A, const unsigned short* __restrict__ B,
    float* __restrict__ C, int M, int K, int NT) {
  __shared__ __align__(16) unsigned short As[2][256 * 64];
  __shared__ __align__(16) unsigned short Bs[2][256 * 64];
  const int nbn = M >> 8;
  const int cpx = gridDim.x >> 3;
  int bid = blockIdx.x;
  bid = (bid & 7) * cpx + (bid >> 3);  // XCD swizzle (grid % 8 == 0)
  const int brow = (bid / nbn) << 8;
  const int bcol = (bid % nbn) << 8;
  const int tid = threadIdx.x;
  const int lane = tid & 63;
  const int w = tid >> 6;  // 8 waves: 2 (M) x 4 (N)
  const int wm = w >> 2;
  const int wn = w & 3;
  const int fr = lane & 15;
  const int lhi = lane >> 4;

  const unsigned short* Abase = A + (size_t)brow * K;
  const unsigned short* Bbase = B + (size_t)bcol * K;

  f32x4 acc[8][4];
#pragma unroll
  for (int i = 0; i < 8; i++)
#pragma unroll
    for (int j = 0; j < 4; j++) acc[i][j] = (f32x4){0.f, 0.f, 0.f, 0.f};
  bf16x8 ahA[4][2], ahB[4][2], bv0A[2][2], bv0B[2][2], bv1[2][2];

  // Prologue: stage buf0 tile0 (A0,B0,B1,A1) then buf1 tile1 (A0,B0,B1).
  STAGE_A(0, 0, 0);
  STAGE_B(0, 0, 0);
  STAGE_B(0, 1, 0);
  STAGE_A(0, 1, 0);
  STAGE_A(1, 0, 1);
  STAGE_B(1, 0, 1);
  STAGE_B(1, 1, 1);
  GATE10();  // drain b0.A0, b0.B0
  BARRIER();
  LOAD_A(0, 0, ahA);
  LOAD_B(0, 0, bv0A);
  GATE8();  // drain b0.B1 (for P1's read, after barrier)
  BARRIER();

  const int NTT = NT / 2;
#pragma unroll 1
  for (int t = 0; t < NTT; ++t) {
    const bool last = (t == NTT - 1);
    const int u1 = 2 * t + 1, u2 = 2 * t + 2, u3 = 2 * t + 3;
    // P1: read b0.B1 (for P2); stage b1.A1 <- u1 (always exists)
    LOAD_B(0, 1, bv1);
    STAGE_A(1, 1, u1);
    BARRIER();
    MFMA_PH(0, 0, ahA, bv0A);
    GATE8();  // covers P2's read of b0.A1
    BARRIER();
    // P2: read b0.A1 (for P3/P4); stage b0.A0 <- u2
    LOAD_A(0, 1, ahB);
    if (!last) STAGE_A(0, 0, u2);
    BARRIER();
    MFMA_PH(0, 1, ahA, bv1);
    BARRIER();
    // P3: stage b0.B0 <- u2
    if (!last) STAGE_B(0, 0, u2);
    BARRIER();
    MFMA_PH(1, 1, ahB, bv1);
    if (!last) { GATE8(); } else { GATE4(); }  // covers P4: b1.A0, b1.B0
    BARRIER();
    // P4: read b1.A0 + b1.B0 (for P5); stage b0.B1 <- u2
    LOAD_A(1, 0, ahA);
    LOAD_B(1, 0, bv0B);
    if (!last) STAGE_B(0, 1, u2);
    BARRIER();
    MFMA_PH(1, 0, ahB, bv0A);
    if (!last) { GATE8(); } else { GATE2(); }  // covers P5: b1.B1
    BARRIER();
    // P5: read b1.B1 (for P6); stage b0.A1 <- u2
    LOAD_B(1, 1, bv1);
    if (!last) STAGE_A(0, 1, u2);
    BARRIER();
    MFMA_PH(0, 0, ahA, bv0B);
    if (!last) { GATE8(); } else { GATE0(); }  // covers P6: b1.A1
    BARRIER();
    // P6: read b1.A1 (for P7/P8); stage b1.A0 <- u3
    LOAD_A(1, 1, ahB);
    if (!last) STAGE_A(1, 0, u3);
    BARRIER();
    MFMA_PH(0, 1, ahA, bv1);
    BARRIER();
    // P7: stage b1.B0 <- u3
    if (!last) STAGE_B(1, 0, u3);
    BARRIER();
    MFMA_PH(1, 1, ahB, bv1);
    if (!last) GATE8();  // covers P8: b0.A0, b0.B0
    BARRIER();
    // P8: read b0.A0 + b0.B0 of tile u2 (for P1'); stage b1.B1 <- u3
    if (!last) {
      LOAD_A(0, 0, ahA);
      LOAD_B(0, 0, bv0A);
      STAGE_B(1, 1, u3);
    }
    BARRIER();
    MFMA_PH(1, 0, ahB, bv0B);
    if (!last) GATE8();  // covers P1': b0.B1 (staged P4)
    BARRIER();
  }

  // Epilogue: C/D layout col=lane&15, row=(lane>>4)*4+q  [m89-verified]
  const int crow0 = brow + wm * 128 + lhi * 4;
  const int ccol0 = bcol + wn * 64 + fr;
#pragma unroll
  for (int mi = 0; mi < 8; mi++)
#pragma unroll
    for (int nj = 0; nj < 4; nj++)
#pragma unroll
      for (int q = 0; q < 4; q++)
        C[(size_t)(crow0 + mi * 16 + q) * M + ccol0 + nj * 16] = acc[mi][nj][q];
}

// ---------------- FWHT #2 (in-place on d_out): out = fwht(Y)*0.5*SV ------
__global__ __launch_bounds__(256) void fwht2_kernel(
    float* __restrict__ Y, const float* __restrict__ SV) {
  __shared__ float lds[256 * 17];
  const int t = threadIdx.x;
  const size_t row = blockIdx.x;
  float* yr = Y + row * 4096;
  float v[16];
#pragma unroll
  for (int n2 = 0; n2 < 16; n2++) v[n2] = yr[n2 * 256 + t];
  fwht16(v);
  const int n1 = t >> 4, n0 = t & 15;
#pragma unroll
  for (int j2 = 0; j2 < 16; j2++) lds[(j2 * 16 + n1) * 17 + n0] = v[j2];
  __syncthreads();
#pragma unroll
  for (int k = 0; k < 16; k++) v[k] = lds[((t >> 4) * 16 + k) * 17 + (t & 15)];
  fwht16(v);
#pragma unroll
  for (int k = 0; k < 16; k++) lds[((t >> 4) * 16 + k) * 17 + (t & 15)] = v[k];
  __syncthreads();
#pragma unroll
  for (int k = 0; k < 16; k++) v[k] = lds[t * 17 + k];
  fwht16(v);
  float outv[16];
#pragma unroll
  for (int k = 0; k < 16; k++) outv[k] = v[k] * 0.5f * SV[(size_t)t * 16 + k];
  float4* dst = (float4*)(yr + (size_t)t * 16);
#pragma unroll
  for (int k = 0; k < 4; k++)
    dst[k] = make_float4(outv[4 * k], outv[4 * k + 1], outv[4 * k + 2],
                         outv[4 * k + 3]);
}

extern "C" void kernel_launch(void* const* d_in, const int* in_sizes, int n_in,
                              void* d_out, int out_size, void* d_ws,
                              size_t ws_size, hipStream_t stream) {
  const float* x = (const float*)d_in[0];
  const float* W = (const float*)d_in[1];
  const float* SU = (const float*)d_in[2];
  const float* SV = (const float*)d_in[3];
  const float* Wscale = (const float*)d_in[4];
  const int N = in_sizes[2];      // 4096
  const int M = in_sizes[3];      // 4096
  const int T = in_sizes[0] / N;  // 16384

  unsigned short* H1 = (unsigned short*)d_ws;
  unsigned short* Wb = H1 + (size_t)T * N;
  float* out = (float*)d_out;

  fwht1_kernel<<<T, 256, 0, stream>>>(x, SU, H1);
  const int total4 = (int)(((long)M * N) / 4);
  convw_kernel<<<(total4 + 255) / 256, 256, 0, stream>>>(
      (const float4*)W, Wscale, (uint2*)Wb, total4, N / 4);
  const int NT = N / 64;  // 64 K-tiles
  gemm8_kernel<<<(T / 256) * (M / 256), 512, 0, stream>>>(H1, Wb, out, M, N, NT);
  fwht2_kernel<<<T, 256, 0, stream>>>(out, SV);
}

// Round 5
// 806.787 us; speedup vs baseline: 1.6791x; 1.6791x over previous
//
#include <hip/hip_runtime.h>
#include <hip/hip_bf16.h>

typedef __bf16 bf16x8 __attribute__((ext_vector_type(8)));
typedef float f32x4 __attribute__((ext_vector_type(4)));

__device__ __forceinline__ void gload16(const void* g, void* l) {
  __builtin_amdgcn_global_load_lds(
      (const __attribute__((address_space(1))) void*)g,
      (__attribute__((address_space(3))) void*)l, 16, 0, 0);
}

__device__ __forceinline__ unsigned short f2bf(float f) {
  __hip_bfloat16 h = __float2bfloat16(f);
  union { __hip_bfloat16 h; unsigned short u; } c;
  c.h = h;
  return c.u;
}

__device__ __forceinline__ void fwht16(float v[16]) {
#pragma unroll
  for (int s = 1; s < 16; s <<= 1) {
#pragma unroll
    for (int i = 0; i < 16; i++) {
      if ((i & s) == 0) {
        float a = v[i], b = v[i | s];
        v[i] = a + b;
        v[i | s] = a - b;
      }
    }
  }
}

// ---------------- FWHT #1: h1 = bf16( fwht(x*SU) / 2048 ) ----------------
__global__ __launch_bounds__(256) void fwht1_kernel(
    const float* __restrict__ x, const float* __restrict__ SU,
    unsigned short* __restrict__ H1) {
  __shared__ float lds[256 * 17];
  const int t = threadIdx.x;
  const size_t row = blockIdx.x;
  const float* xr = x + row * 4096;
  float v[16];
#pragma unroll
  for (int n2 = 0; n2 < 16; n2++) {
    int n = n2 * 256 + t;
    v[n2] = xr[n] * SU[n];
  }
  fwht16(v);
  const int n1 = t >> 4, n0 = t & 15;
#pragma unroll
  for (int j2 = 0; j2 < 16; j2++) lds[(j2 * 16 + n1) * 17 + n0] = v[j2];
  __syncthreads();
#pragma unroll
  for (int k = 0; k < 16; k++) v[k] = lds[((t >> 4) * 16 + k) * 17 + (t & 15)];
  fwht16(v);
#pragma unroll
  for (int k = 0; k < 16; k++) lds[((t >> 4) * 16 + k) * 17 + (t & 15)] = v[k];
  __syncthreads();
#pragma unroll
  for (int k = 0; k < 16; k++) v[k] = lds[t * 17 + k];
  fwht16(v);
  const float cst = 1.0f / 2048.0f;
  union { unsigned short u[16]; uint4 q[2]; } o;
#pragma unroll
  for (int k = 0; k < 16; k++) o.u[k] = f2bf(v[k] * cst);
  uint4* dst = (uint4*)(H1 + row * 4096 + (size_t)t * 16);
  dst[0] = o.q[0];
  dst[1] = o.q[1];
}

// ---------------- W conversion: Wb[m][n] = bf16(W[m][n] * Wscale[m]) -------
__global__ __launch_bounds__(256) void convw_kernel(
    const float4* __restrict__ W4, const float* __restrict__ Wscale,
    uint2* __restrict__ Wb4, int total4, int Nq) {
  int i = blockIdx.x * 256 + threadIdx.x;
  if (i >= total4) return;
  float4 w = W4[i];
  float s = Wscale[i / Nq];
  unsigned int lo = (unsigned)f2bf(w.x * s) | ((unsigned)f2bf(w.y * s) << 16);
  unsigned int hi = (unsigned)f2bf(w.z * s) | ((unsigned)f2bf(w.w * s) << 16);
  Wb4[i] = make_uint2(lo, hi);
}

// ---------------- GEMM: 256x256, BK=64, 8 waves, 8-phase, FUSED read+MFMA --
// Phase = {GATE?; BARRIER; STAGE(2 gloads); ds_reads; MFMA} with NO fence
// between reads and MFMA -> compiler emits counted lgkmcnt so MFMA overlaps
// the LDS reads (the R2 structure serialized them across a fenced barrier).
// One barrier/phase (8/iter). Hazards:
//  - RAW (read staged data): whole-buffer vmcnt gates before the barrier
//    preceding the reads (GATE2 steady state: drain 8 oldest = that buffer).
//  - WAR (restage over read): a wave's reads are lgkm-drained before it
//    reaches the next barrier (MFMA consumes them); stages issue only after
//    that barrier. b0 last read P3, restaged P4+; b1 last read P7, restaged P8+.
// Stage slots/iter: P1,P2,P3 = b1<-2t+1 (A1,B0,B1), P4..P7 = b0<-2t+2
// (A0,A1,B0,B1), P8 = b1.A0<-2t+3.  Tail: skip invalid stages, P5 gate=0.

#define BARRIER()                          \
  do {                                     \
    asm volatile("" ::: "memory");         \
    __builtin_amdgcn_s_barrier();          \
    asm volatile("" ::: "memory");         \
  } while (0)
#define GATE2() asm volatile("s_waitcnt vmcnt(2)" ::: "memory")
#define GATE0() asm volatile("s_waitcnt vmcnt(0)" ::: "memory")

// 128-row half-tile (16KB): 2 gload16/thread. LDS dest linear; global source
// pre-swizzled so ds_read applies chunk ^= (row&7) (both-sides involution).
__device__ __forceinline__ void stage_half(const unsigned short* __restrict__ g,
                                           unsigned short* l, int tid, int K) {
#pragma unroll
  for (int i = 0; i < 2; i++) {
    int idx = i * 512 + tid;
    int r = idx >> 3;
    int c = (idx & 7) ^ (r & 7);
    gload16(g + (size_t)r * K + c * 8, l + idx * 8);
  }
}

#define STAGE_A(d, hh, kt) \
  stage_half(Abase + (size_t)(hh)*128 * K + (size_t)(kt)*64, &As[d][(hh)*8192], tid, K)
#define STAGE_B(d, hh, kt) \
  stage_half(Bbase + (size_t)(hh)*128 * K + (size_t)(kt)*64, &Bs[d][(hh)*8192], tid, K)

#define LOAD_A(d, h)                                                          \
  {                                                                           \
    _Pragma("unroll") for (int i = 0; i < 4; i++) {                           \
      _Pragma("unroll") for (int ks = 0; ks < 2; ks++) {                      \
        int r = wm * 128 + (h)*64 + i * 16 + fr;                              \
        int kc = ks * 4 + lhi;                                                \
        ah[i][ks] = *(const bf16x8*)&As[d][r * 64 + ((kc ^ (r & 7)) << 3)];   \
      }                                                                       \
    }                                                                         \
  }

#define LOAD_B(d, v, dst)                                                     \
  {                                                                           \
    _Pragma("unroll") for (int j = 0; j < 2; j++) {                           \
      _Pragma("unroll") for (int ks = 0; ks < 2; ks++) {                      \
        int r = wn * 64 + (v)*32 + j * 16 + fr;                               \
        int kc = ks * 4 + lhi;                                                \
        dst[j][ks] = *(const bf16x8*)&Bs[d][r * 64 + ((kc ^ (r & 7)) << 3)];  \
      }                                                                       \
    }                                                                         \
  }

#define MFMA_PH(h, v, bvx)                                                    \
  {                                                                           \
    __builtin_amdgcn_s_setprio(1);                                            \
    _Pragma("unroll") for (int i = 0; i < 4; i++)                             \
      _Pragma("unroll") for (int j = 0; j < 2; j++)                           \
        _Pragma("unroll") for (int ks = 0; ks < 2; ks++)                      \
          acc[(h)*4 + i][(v)*2 + j] = __builtin_amdgcn_mfma_f32_16x16x32_bf16( \
              ah[i][ks], bvx[j][ks], acc[(h)*4 + i][(v)*2 + j], 0, 0, 0);     \
    __builtin_amdgcn_s_setprio(0);                                            \
  }

__global__ __launch_bounds__(512, 2) void gemm8_kernel(
    const unsigned short* __restrict__ A, const unsigned short* __restrict__ B,
    float* __restrict__ C, int M, int K, int NT) {
  __shared__ __align__(16) unsigned short As[2][256 * 64];
  __shared__ __align__(16) unsigned short Bs[2][256 * 64];
  const int nbn = M >> 8;
  const int cpx = gridDim.x >> 3;
  int bid = blockIdx.x;
  bid = (bid & 7) * cpx + (bid >> 3);  // XCD swizzle (grid % 8 == 0)
  const int brow = (bid / nbn) << 8;
  const int bcol = (bid % nbn) << 8;
  const int tid = threadIdx.x;
  const int lane = tid & 63;
  const int w = tid >> 6;  // 8 waves: 2 (M) x 4 (N)
  const int wm = w >> 2;
  const int wn = w & 3;
  const int fr = lane & 15;
  const int lhi = lane >> 4;

  const unsigned short* Abase = A + (size_t)brow * K;
  const unsigned short* Bbase = B + (size_t)bcol * K;

  f32x4 acc[8][4];
#pragma unroll
  for (int i = 0; i < 8; i++)
#pragma unroll
    for (int j = 0; j < 4; j++) acc[i][j] = (f32x4){0.f, 0.f, 0.f, 0.f};
  bf16x8 ah[4][2], bv0[2][2], bv1[2][2];

  // Prologue: b0 <- tile0 (A0,A1,B0,B1 = 8 loads), then b1.A0 <- tile1 (2).
  // Entering P1: outstanding 10, GATE2 drains the 8 oldest (= all of b0).
  STAGE_A(0, 0, 0);
  STAGE_A(0, 1, 0);
  STAGE_B(0, 0, 0);
  STAGE_B(0, 1, 0);
  STAGE_A(1, 0, 1);

  const int NTT = NT / 2;
#pragma unroll 1
  for (int t = 0; t < NTT; ++t) {
    const bool last = (t == NTT - 1);
    const int u1 = 2 * t + 1, u2 = 2 * t + 2, u3 = 2 * t + 3;
    // P1: reads b0 A-h0 + B-v0
    GATE2();
    BARRIER();
    STAGE_A(1, 1, u1);
    LOAD_A(0, 0);
    LOAD_B(0, 0, bv0);
    MFMA_PH(0, 0, bv0);
    // P2: reads b0 B-v1
    BARRIER();
    STAGE_B(1, 0, u1);
    LOAD_B(0, 1, bv1);
    MFMA_PH(0, 1, bv1);
    // P3: reads b0 A-h1 (last b0 read)
    BARRIER();
    STAGE_B(1, 1, u1);
    LOAD_A(0, 1);
    MFMA_PH(1, 1, bv1);
    // P4: no reads (ah=h1, bv0 live since P1); restage b0 begins
    BARRIER();
    if (!last) STAGE_A(0, 0, u2);
    MFMA_PH(1, 0, bv0);
    // P5: reads b1 A-h0 + B-v0
    if (last) { GATE0(); } else { GATE2(); }
    BARRIER();
    if (!last) STAGE_A(0, 1, u2);
    LOAD_A(1, 0);
    LOAD_B(1, 0, bv0);
    MFMA_PH(0, 0, bv0);
    // P6: reads b1 B-v1
    BARRIER();
    if (!last) STAGE_B(0, 0, u2);
    LOAD_B(1, 1, bv1);
    MFMA_PH(0, 1, bv1);
    // P7: reads b1 A-h1 (last b1 read)
    BARRIER();
    if (!last) STAGE_B(0, 1, u2);
    LOAD_A(1, 1);
    MFMA_PH(1, 1, bv1);
    // P8: no reads; b1 restage begins
    BARRIER();
    if (!last) STAGE_A(1, 0, u3);
    MFMA_PH(1, 0, bv0);
  }

  // Epilogue: C/D layout col=lane&15, row=(lane>>4)*4+q  [m89-verified]
  const int crow0 = brow + wm * 128 + lhi * 4;
  const int ccol0 = bcol + wn * 64 + fr;
#pragma unroll
  for (int mi = 0; mi < 8; mi++)
#pragma unroll
    for (int nj = 0; nj < 4; nj++)
#pragma unroll
      for (int q = 0; q < 4; q++)
        C[(size_t)(crow0 + mi * 16 + q) * M + ccol0 + nj * 16] = acc[mi][nj][q];
}

// ---------------- FWHT #2 (in-place on d_out): out = fwht(Y)*0.5*SV ------
__global__ __launch_bounds__(256) void fwht2_kernel(
    float* __restrict__ Y, const float* __restrict__ SV) {
  __shared__ float lds[256 * 17];
  const int t = threadIdx.x;
  const size_t row = blockIdx.x;
  float* yr = Y + row * 4096;
  float v[16];
#pragma unroll
  for (int n2 = 0; n2 < 16; n2++) v[n2] = yr[n2 * 256 + t];
  fwht16(v);
  const int n1 = t >> 4, n0 = t & 15;
#pragma unroll
  for (int j2 = 0; j2 < 16; j2++) lds[(j2 * 16 + n1) * 17 + n0] = v[j2];
  __syncthreads();
#pragma unroll
  for (int k = 0; k < 16; k++) v[k] = lds[((t >> 4) * 16 + k) * 17 + (t & 15)];
  fwht16(v);
#pragma unroll
  for (int k = 0; k < 16; k++) lds[((t >> 4) * 16 + k) * 17 + (t & 15)] = v[k];
  __syncthreads();
#pragma unroll
  for (int k = 0; k < 16; k++) v[k] = lds[t * 17 + k];
  fwht16(v);
  float outv[16];
#pragma unroll
  for (int k = 0; k < 16; k++) outv[k] = v[k] * 0.5f * SV[(size_t)t * 16 + k];
  float4* dst = (float4*)(yr + (size_t)t * 16);
#pragma unroll
  for (int k = 0; k < 4; k++)
    dst[k] = make_float4(outv[4 * k], outv[4 * k + 1], outv[4 * k + 2],
                         outv[4 * k + 3]);
}

extern "C" void kernel_launch(void* const* d_in, const int* in_sizes, int n_in,
                              void* d_out, int out_size, void* d_ws,
                              size_t ws_size, hipStream_t stream) {
  const float* x = (const float*)d_in[0];
  const float* W = (const float*)d_in[1];
  const float* SU = (const float*)d_in[2];
  const float* SV = (const float*)d_in[3];
  const float* Wscale = (const float*)d_in[4];
  const int N = in_sizes[2];      // 4096
  const int M = in_sizes[3];      // 4096
  const int T = in_sizes[0] / N;  // 16384

  unsigned short* H1 = (unsigned short*)d_ws;
  unsigned short* Wb = H1 + (size_t)T * N;
  float* out = (float*)d_out;

  fwht1_kernel<<<T, 256, 0, stream>>>(x, SU, H1);
  const int total4 = (int)(((long)M * N) / 4);
  convw_kernel<<<(total4 + 255) / 256, 256, 0, stream>>>(
      (const float4*)W, Wscale, (uint2*)Wb, total4, N / 4);
  const int NT = N / 64;  // 64 K-tiles
  gemm8_kernel<<<(T / 256) * (M / 256), 512, 0, stream>>>(H1, Wb, out, M, N, NT);
  fwht2_kernel<<<T, 256, 0, stream>>>(out, SV);
}

// Round 6
// 758.936 us; speedup vs baseline: 1.7850x; 1.0631x over previous
//
#include <hip/hip_runtime.h>
#include <hip/hip_bf16.h>

typedef __bf16 bf16x8 __attribute__((ext_vector_type(8)));
typedef float f32x4 __attribute__((ext_vector_type(4)));

__device__ __forceinline__ void gload16(const void* g, void* l) {
  __builtin_amdgcn_global_load_lds(
      (const __attribute__((address_space(1))) void*)g,
      (__attribute__((address_space(3))) void*)l, 16, 0, 0);
}

__device__ __forceinline__ unsigned short f2bf(float f) {
  __hip_bfloat16 h = __float2bfloat16(f);
  union { __hip_bfloat16 h; unsigned short u; } c;
  c.h = h;
  return c.u;
}

__device__ __forceinline__ void fwht16(float v[16]) {
#pragma unroll
  for (int s = 1; s < 16; s <<= 1) {
#pragma unroll
    for (int i = 0; i < 16; i++) {
      if ((i & s) == 0) {
        float a = v[i], b = v[i | s];
        v[i] = a + b;
        v[i | s] = a - b;
      }
    }
  }
}

// ---------------- FWHT #1: h1 = bf16( fwht(x*SU) / 2048 ) ----------------
__global__ __launch_bounds__(256) void fwht1_kernel(
    const float* __restrict__ x, const float* __restrict__ SU,
    unsigned short* __restrict__ H1) {
  __shared__ float lds[256 * 17];
  const int t = threadIdx.x;
  const size_t row = blockIdx.x;
  const float* xr = x + row * 4096;
  float v[16];
#pragma unroll
  for (int n2 = 0; n2 < 16; n2++) {
    int n = n2 * 256 + t;
    v[n2] = xr[n] * SU[n];
  }
  fwht16(v);
  const int n1 = t >> 4, n0 = t & 15;
#pragma unroll
  for (int j2 = 0; j2 < 16; j2++) lds[(j2 * 16 + n1) * 17 + n0] = v[j2];
  __syncthreads();
#pragma unroll
  for (int k = 0; k < 16; k++) v[k] = lds[((t >> 4) * 16 + k) * 17 + (t & 15)];
  fwht16(v);
#pragma unroll
  for (int k = 0; k < 16; k++) lds[((t >> 4) * 16 + k) * 17 + (t & 15)] = v[k];
  __syncthreads();
#pragma unroll
  for (int k = 0; k < 16; k++) v[k] = lds[t * 17 + k];
  fwht16(v);
  const float cst = 1.0f / 2048.0f;
  union { unsigned short u[16]; uint4 q[2]; } o;
#pragma unroll
  for (int k = 0; k < 16; k++) o.u[k] = f2bf(v[k] * cst);
  uint4* dst = (uint4*)(H1 + row * 4096 + (size_t)t * 16);
  dst[0] = o.q[0];
  dst[1] = o.q[1];
}

// ---------------- W conversion: Wb[m][n] = bf16(W[m][n] * Wscale[m]) -------
__global__ __launch_bounds__(256) void convw_kernel(
    const float4* __restrict__ W4, const float* __restrict__ Wscale,
    uint2* __restrict__ Wb4, int total4, int Nq) {
  int i = blockIdx.x * 256 + threadIdx.x;
  if (i >= total4) return;
  float4 w = W4[i];
  float s = Wscale[i / Nq];
  unsigned int lo = (unsigned)f2bf(w.x * s) | ((unsigned)f2bf(w.y * s) << 16);
  unsigned int hi = (unsigned)f2bf(w.z * s) | ((unsigned)f2bf(w.w * s) << 16);
  Wb4[i] = make_uint2(lo, hi);
}

// ---------------- GEMM: 256x256, BK=64, 8 waves, 8-phase (m201 template) ---
// CRITICAL: raw s_barrier + bare-asm waitcnt (NO "memory" clobbers). A memory
// clobber makes the backend insert s_waitcnt vmcnt(0) lgkmcnt(0) before the
// asm, draining the global_load_lds queue at every barrier and killing the
// counted-vmcnt pipeline (T4) — that was R2-R5's 40% ceiling.
// Phase = {ds-reads; stage 1 half-tile; [lgkm8 if 12 reads]; barrier;
//          lgkm0; setprio(1); 16 MFMA; setprio(0); barrier}.
// Stage slots/iter (1 half/phase, 2 loads): P1-P3 finish b1<-2t+1, P4-P7
// stage b0<-2t+2, P8 starts b1<-2t+3. Gates vmcnt(2) at P4/P8 only:
// 10 outstanding, drain 8 oldest = exactly the tile about to be read.
// Tail: P4 gate = vmcnt(0), stages skipped.

#define BAR() __builtin_amdgcn_s_barrier()
#define SCHED() __builtin_amdgcn_sched_barrier(0)
#define GATE2()                              \
  do {                                       \
    SCHED();                                 \
    asm volatile("s_waitcnt vmcnt(2)");      \
    SCHED();                                 \
  } while (0)
#define GATE0()                              \
  do {                                       \
    SCHED();                                 \
    asm volatile("s_waitcnt vmcnt(0)");      \
    SCHED();                                 \
  } while (0)
#define LGKM0() asm volatile("s_waitcnt lgkmcnt(0)")
#define LGKM8() asm volatile("s_waitcnt lgkmcnt(8)")

// 128-row half-tile (16KB): 2 gload16/thread. LDS dest linear; global source
// pre-swizzled so ds_read applies chunk ^= (row&7) (both-sides involution).
__device__ __forceinline__ void stage_half(const unsigned short* __restrict__ g,
                                           unsigned short* l, int tid, int K) {
#pragma unroll
  for (int i = 0; i < 2; i++) {
    int idx = i * 512 + tid;
    int r = idx >> 3;
    int c = (idx & 7) ^ (r & 7);
    gload16(g + (size_t)r * K + c * 8, l + idx * 8);
  }
}

#define STAGE_A(d, hh, kt) \
  stage_half(Abase + (size_t)(hh)*128 * K + (size_t)(kt)*64, &As[d][(hh)*8192], tid, K)
#define STAGE_B(d, hh, kt) \
  stage_half(Bbase + (size_t)(hh)*128 * K + (size_t)(kt)*64, &Bs[d][(hh)*8192], tid, K)

// Read A m-sub (m=0/1: rows wm*128+m*64 .. +63) of buf d -> ah[4][2].
#define LOAD_A(d, m)                                                          \
  {                                                                           \
    _Pragma("unroll") for (int i = 0; i < 4; i++) {                           \
      _Pragma("unroll") for (int ks = 0; ks < 2; ks++) {                      \
        int r = wm * 128 + (m)*64 + i * 16 + fr;                              \
        int kc = ks * 4 + lhi;                                                \
        ah[i][ks] = *(const bf16x8*)&As[d][r * 64 + ((kc ^ (r & 7)) << 3)];   \
      }                                                                       \
    }                                                                         \
  }

// Read B n-sub (v=0/1: cols wn*64+v*32 .. +31) of buf d -> dst[2][2].
#define LOAD_B(d, v, dst)                                                     \
  {                                                                           \
    _Pragma("unroll") for (int j = 0; j < 2; j++) {                           \
      _Pragma("unroll") for (int ks = 0; ks < 2; ks++) {                      \
        int r = wn * 64 + (v)*32 + j * 16 + fr;                               \
        int kc = ks * 4 + lhi;                                                \
        dst[j][ks] = *(const bf16x8*)&Bs[d][r * 64 + ((kc ^ (r & 7)) << 3)];  \
      }                                                                       \
    }                                                                         \
  }

#define MFMA_PH(m, v, bvx)                                                    \
  {                                                                           \
    __builtin_amdgcn_s_setprio(1);                                            \
    _Pragma("unroll") for (int i = 0; i < 4; i++)                             \
      _Pragma("unroll") for (int j = 0; j < 2; j++)                           \
        _Pragma("unroll") for (int ks = 0; ks < 2; ks++)                      \
          acc[(m)*4 + i][(v)*2 + j] = __builtin_amdgcn_mfma_f32_16x16x32_bf16( \
              ah[i][ks], bvx[j][ks], acc[(m)*4 + i][(v)*2 + j], 0, 0, 0);     \
    __builtin_amdgcn_s_setprio(0);                                            \
  }

__global__ __launch_bounds__(512, 2) void gemm8_kernel(
    const unsigned short* __restrict__ A, const unsigned short* __restrict__ B,
    float* __restrict__ C, int M, int K, int NT) {
  __shared__ __align__(16) unsigned short As[2][256 * 64];
  __shared__ __align__(16) unsigned short Bs[2][256 * 64];
  const int nbn = M >> 8;
  const int cpx = gridDim.x >> 3;
  int bid = blockIdx.x;
  bid = (bid & 7) * cpx + (bid >> 3);  // XCD swizzle (grid % 8 == 0)
  const int brow = (bid / nbn) << 8;
  const int bcol = (bid % nbn) << 8;
  const int tid = threadIdx.x;
  const int lane = tid & 63;
  const int w = tid >> 6;  // 8 waves: 2 (M) x 4 (N)
  const int wm = w >> 2;
  const int wn = w & 3;
  const int fr = lane & 15;
  const int lhi = lane >> 4;

  const unsigned short* Abase = A + (size_t)brow * K;
  const unsigned short* Bbase = B + (size_t)bcol * K;

  f32x4 acc[8][4];
#pragma unroll
  for (int i = 0; i < 8; i++)
#pragma unroll
    for (int j = 0; j < 4; j++) acc[i][j] = (f32x4){0.f, 0.f, 0.f, 0.f};
  bf16x8 ah[4][2], bv0[2][2], bv1[2][2];

  // Prologue: b0 <- tile0 (4 halves, 8 loads); b1.H1 <- tile1 (2 loads).
  // Gate: 10 outstanding, drain 8 oldest (= all of b0) -> vmcnt(2).
  STAGE_A(0, 0, 0);
  STAGE_A(0, 1, 0);
  STAGE_B(0, 0, 0);
  STAGE_B(0, 1, 0);
  STAGE_A(1, 0, 1);
  GATE2();
  BAR();

  const int NTT = NT / 2;
#pragma unroll 1
  for (int t = 0; t < NTT; ++t) {
    const bool last = (t == NTT - 1);
    const int u1 = 2 * t + 1, u2 = 2 * t + 2, u3 = 2 * t + 3;
    // P1: reads b0 A[m0]+B[n0] (12); stage b1.H2 <- u1
    LOAD_A(0, 0);
    LOAD_B(0, 0, bv0);
    STAGE_A(1, 1, u1);
    LGKM8();
    BAR();
    LGKM0();
    MFMA_PH(0, 0, bv0);
    BAR();
    // P2: reads b0 B[n1] (4); stage b1.H3 <- u1
    LOAD_B(0, 1, bv1);
    STAGE_B(1, 0, u1);
    BAR();
    LGKM0();
    MFMA_PH(0, 1, bv1);
    BAR();
    // P3: reads b0 A[m1] (8); stage b1.H4 <- u1 (tile u1 fully issued)
    LOAD_A(0, 1);
    STAGE_B(1, 1, u1);
    BAR();
    LGKM0();
    MFMA_PH(1, 1, bv1);
    BAR();
    // P4: no reads; stage b0.H1 <- u2; GATE for b1 (drain tile u1's 8)
    if (!last) {
      STAGE_A(0, 0, u2);
      GATE2();
    } else {
      GATE0();
    }
    BAR();
    MFMA_PH(1, 0, bv0);
    BAR();
    // P5: reads b1 A[m0]+B[n0] (12); stage b0.H2 <- u2
    LOAD_A(1, 0);
    LOAD_B(1, 0, bv0);
    if (!last) STAGE_A(0, 1, u2);
    LGKM8();
    BAR();
    LGKM0();
    MFMA_PH(0, 0, bv0);
    BAR();
    // P6: reads b1 B[n1] (4); stage b0.H3 <- u2
    LOAD_B(1, 1, bv1);
    if (!last) STAGE_B(0, 0, u2);
    BAR();
    LGKM0();
    MFMA_PH(0, 1, bv1);
    BAR();
    // P7: reads b1 A[m1] (8); stage b0.H4 <- u2 (tile u2 fully issued)
    LOAD_A(1, 1);
    if (!last) STAGE_B(0, 1, u2);
    BAR();
    LGKM0();
    MFMA_PH(1, 1, bv1);
    BAR();
    // P8: no reads; stage b1.H1 <- u3; GATE for b0 (drain tile u2's 8)
    if (!last) {
      STAGE_A(1, 0, u3);
      GATE2();
    }
    BAR();
    MFMA_PH(1, 0, bv0);
    BAR();
  }

  // Epilogue: C/D layout col=lane&15, row=(lane>>4)*4+q  [m89-verified]
  const int crow0 = brow + wm * 128 + lhi * 4;
  const int ccol0 = bcol + wn * 64 + fr;
#pragma unroll
  for (int mi = 0; mi < 8; mi++)
#pragma unroll
    for (int nj = 0; nj < 4; nj++)
#pragma unroll
      for (int q = 0; q < 4; q++)
        C[(size_t)(crow0 + mi * 16 + q) * M + ccol0 + nj * 16] = acc[mi][nj][q];
}

// ---------------- FWHT #2 (in-place on d_out): out = fwht(Y)*0.5*SV ------
__global__ __launch_bounds__(256) void fwht2_kernel(
    float* __restrict__ Y, const float* __restrict__ SV) {
  __shared__ float lds[256 * 17];
  const int t = threadIdx.x;
  const size_t row = blockIdx.x;
  float* yr = Y + row * 4096;
  float v[16];
#pragma unroll
  for (int n2 = 0; n2 < 16; n2++) v[n2] = yr[n2 * 256 + t];
  fwht16(v);
  const int n1 = t >> 4, n0 = t & 15;
#pragma unroll
  for (int j2 = 0; j2 < 16; j2++) lds[(j2 * 16 + n1) * 17 + n0] = v[j2];
  __syncthreads();
#pragma unroll
  for (int k = 0; k < 16; k++) v[k] = lds[((t >> 4) * 16 + k) * 17 + (t & 15)];
  fwht16(v);
#pragma unroll
  for (int k = 0; k < 16; k++) lds[((t >> 4) * 16 + k) * 17 + (t & 15)] = v[k];
  __syncthreads();
#pragma unroll
  for (int k = 0; k < 16; k++) v[k] = lds[t * 17 + k];
  fwht16(v);
  float outv[16];
#pragma unroll
  for (int k = 0; k < 16; k++) outv[k] = v[k] * 0.5f * SV[(size_t)t * 16 + k];
  float4* dst = (float4*)(yr + (size_t)t * 16);
#pragma unroll
  for (int k = 0; k < 4; k++)
    dst[k] = make_float4(outv[4 * k], outv[4 * k + 1], outv[4 * k + 2],
                         outv[4 * k + 3]);
}

extern "C" void kernel_launch(void* const* d_in, const int* in_sizes, int n_in,
                              void* d_out, int out_size, void* d_ws,
                              size_t ws_size, hipStream_t stream) {
  const float* x = (const float*)d_in[0];
  const float* W = (const float*)d_in[1];
  const float* SU = (const float*)d_in[2];
  const float* SV = (const float*)d_in[3];
  const float* Wscale = (const float*)d_in[4];
  const int N = in_sizes[2];      // 4096
  const int M = in_sizes[3];      // 4096
  const int T = in_sizes[0] / N;  // 16384

  unsigned short* H1 = (unsigned short*)d_ws;
  unsigned short* Wb = H1 + (size_t)T * N;
  float* out = (float*)d_out;

  fwht1_kernel<<<T, 256, 0, stream>>>(x, SU, H1);
  const int total4 = (int)(((long)M * N) / 4);
  convw_kernel<<<(total4 + 255) / 256, 256, 0, stream>>>(
      (const float4*)W, Wscale, (uint2*)Wb, total4, N / 4);
  const int NT = N / 64;  // 64 K-tiles
  gemm8_kernel<<<(T / 256) * (M / 256), 512, 0, stream>>>(H1, Wb, out, M, N, NT);
  fwht2_kernel<<<T, 256, 0, stream>>>(out, SV);
}